// Round 7
// baseline (269.047 us; speedup 1.0000x reference)
//
#include <hip/hip_runtime.h>

typedef __bf16 bf16;
typedef __bf16 bf16x8 __attribute__((ext_vector_type(8)));
typedef float floatx4 __attribute__((ext_vector_type(4)));
typedef float floatx16 __attribute__((ext_vector_type(16)));

static constexpr int S = 2304;     // 48*48 tokens
static constexpr int C = 1024;
static constexpr int NHEAD = 16;
static constexpr int HDIM = 64;
static constexpr int BATCH = 2;
static constexpr float QSCALE = 0.18033688011112042f;  // log2(e)/8
static constexpr int QACC0 = 512;  // accum space starts at q=512 (qt>=2)
static constexpr int NACCQ = S - QACC0;  // 1792 accum q slots
static constexpr int NPART = 3;    // up to 3 k-chunks per accum q-row

// ---------------------------------------------------------------------------
// 0) fp32 -> bf16 convert (weights)
// ---------------------------------------------------------------------------
__global__ __launch_bounds__(256) void k_convert(const float* __restrict__ src,
                                                 bf16* __restrict__ dst, int n8) {
  int i = blockIdx.x * 256 + threadIdx.x;
  if (i >= n8) return;
  float4 a = *(const float4*)(src + (size_t)i * 8);
  float4 b = *(const float4*)(src + (size_t)i * 8 + 4);
  bf16x8 o;
  o[0] = (bf16)a.x; o[1] = (bf16)a.y; o[2] = (bf16)a.z; o[3] = (bf16)a.w;
  o[4] = (bf16)b.x; o[5] = (bf16)b.y; o[6] = (bf16)b.z; o[7] = (bf16)b.w;
  *(bf16x8*)(dst + (size_t)i * 8) = o;
}

// ---------------------------------------------------------------------------
// 1) transpose + cast: x[b][c][t] (fp32) -> xs[(b*S+t)][c] (bf16)
// ---------------------------------------------------------------------------
__global__ __launch_bounds__(256) void k_transpose(const float* __restrict__ x,
                                                   bf16* __restrict__ xs) {
  __shared__ bf16 T[64 * 72];   // [t][c] tile, stride 72
  int c0 = blockIdx.x * 64, t0 = blockIdx.y * 64, b = blockIdx.z;
  int tid = threadIdx.x;
  const float* xb = x + (size_t)b * C * S;
#pragma unroll
  for (int it = 0; it < 4; ++it) {
    int idx = it * 256 + tid;            // 1024 float4 chunks
    int rc = idx >> 4, t4 = idx & 15;    // c-row, t-group-of-4
    float4 v = *(const float4*)(xb + (size_t)(c0 + rc) * S + t0 + t4 * 4);
    T[(t4 * 4 + 0) * 72 + rc] = (bf16)v.x;
    T[(t4 * 4 + 1) * 72 + rc] = (bf16)v.y;
    T[(t4 * 4 + 2) * 72 + rc] = (bf16)v.z;
    T[(t4 * 4 + 3) * 72 + rc] = (bf16)v.w;
  }
  __syncthreads();
  bf16* xsb = xs + (size_t)b * S * C;
#pragma unroll
  for (int it = 0; it < 2; ++it) {
    int idx = it * 256 + tid;            // 512 chunks of 8 c
    int rt = idx >> 3, c8 = idx & 7;
    bf16x8 v;
#pragma unroll
    for (int i = 0; i < 8; ++i) v[i] = T[rt * 72 + c8 * 8 + i];
    *(bf16x8*)(xsb + (size_t)(t0 + rt) * C + c0 + c8 * 8) = v;
  }
}

// ---------------------------------------------------------------------------
// async global->LDS 16B helper
// ---------------------------------------------------------------------------
__device__ __forceinline__ void g2l16(const bf16* g, bf16* l) {
  __builtin_amdgcn_global_load_lds(
      (const __attribute__((address_space(1))) void*)g,
      (__attribute__((address_space(3))) void*)l, 16, 0, 0);
}

// pack 2 f32 -> 1 dword of 2 bf16 (RNE)
__device__ __forceinline__ unsigned cvtpk(float a, float b) {
  unsigned r;
  asm("v_cvt_pk_bf16_f32 %0, %1, %2" : "=v"(r) : "v"(a), "v"(b));
  return r;
}

// swap a.hi32lanes <-> b.lo32lanes
__device__ __forceinline__ void pl32(unsigned& a, unsigned& b) {
  asm("v_permlane32_swap_b32 %0, %1" : "+v"(a), "+v"(b));
}

// ---------------------------------------------------------------------------
// 2/4) GEMM  C[m][n] = A[m][:] . Bt[n][:]  (+fp32 bias, fused epilogue)
//   128x128 tile, BK=64, XOR-swizzled 16B chunks (conflict-free b128 reads),
//   32 MFMA per barrier pair, 16 K-iterations.   [R5 proven version]
//   EPI 0: qkv -> Q (pre-scaled by log2e/8), K, Vt
//   EPI 1: out-proj -> out[b][co][t] fp32
// ---------------------------------------------------------------------------
template <int EPI>
__global__ __launch_bounds__(256) void k_gemm_bt(const bf16* __restrict__ A,
                                                 const bf16* __restrict__ Bt,
                                                 const float* __restrict__ bias,
                                                 bf16* __restrict__ q,
                                                 bf16* __restrict__ k,
                                                 bf16* __restrict__ v,
                                                 float* __restrict__ outf) {
  constexpr int K = C;
  __shared__ bf16 As[128 * 64];     // [row][64], chunks XOR-swizzled
  __shared__ bf16 Bs[128 * 64];
  int tid = threadIdx.x;
  int w = tid >> 6, lane = tid & 63, ln = lane & 15, quad = lane >> 4;
  int m0 = blockIdx.y * 128, n0 = blockIdx.x * 128;
  int moff = (w >> 1) * 64, noff = (w & 1) * 64;
  floatx4 acc[4][4] = {};

  // staging map: 1024 chunks of 16B per matrix; thread covers 4 each.
  // LDS chunk L = cb + lane holds source chunk (row = L>>3, c8 = (L&7)^(row&7))
  int sr[4], sc[4];
#pragma unroll
  for (int it = 0; it < 4; ++it) {
    int L = (it * 4 + w) * 64 + lane;
    sr[it] = L >> 3;
    sc[it] = (L & 7) ^ (sr[it] & 7);
  }

  for (int k0 = 0; k0 < K; k0 += 64) {
    __syncthreads();
#pragma unroll
    for (int it = 0; it < 4; ++it) {
      int cb = (it * 4 + w) * 64;       // wave-uniform chunk base
      g2l16(A + (size_t)(m0 + sr[it]) * K + k0 + sc[it] * 8, As + cb * 8);
      g2l16(Bt + (size_t)(n0 + sr[it]) * K + k0 + sc[it] * 8, Bs + cb * 8);
    }
    __syncthreads();
#pragma unroll
    for (int t = 0; t < 2; ++t) {       // two k-halves of 32
      bf16x8 af[4], bfr[4];
#pragma unroll
      for (int i = 0; i < 4; ++i) {
        int ra = moff + i * 16 + ln;
        af[i]  = *(const bf16x8*)(As + ra * 64 + (((t * 4 + quad) ^ (ra & 7))) * 8);
        int rb = noff + i * 16 + ln;
        bfr[i] = *(const bf16x8*)(Bs + rb * 64 + (((t * 4 + quad) ^ (rb & 7))) * 8);
      }
#pragma unroll
      for (int im = 0; im < 4; ++im)
#pragma unroll
        for (int in = 0; in < 4; ++in)
          acc[im][in] = __builtin_amdgcn_mfma_f32_16x16x32_bf16(
              af[im], bfr[in], acc[im][in], 0, 0, 0);
    }
  }

  int bidx = (m0 >= S) ? 1 : 0;   // S=2304 = 18*128: tiles never straddle
  if (EPI == 0) {
#pragma unroll
    for (int in = 0; in < 4; ++in) {
      int j = n0 + noff + in * 16 + ln;    // column in [0,3072)
      float bv = bias[j];
      int three = j >> 10;
      int head = (j >> 6) & 15;
      int hdi = j & 63;
#pragma unroll
      for (int im = 0; im < 4; ++im) {
        int mbase = m0 + moff + im * 16 + quad * 4;
        int tb = mbase - bidx * S;
        if (three == 2) {
          union { ushort4 u; bf16 h[4]; } P;
#pragma unroll
          for (int r = 0; r < 4; ++r) P.h[r] = (bf16)(acc[im][in][r] + bv);
          *(ushort4*)(v + ((size_t)(bidx * NHEAD + head) * HDIM + hdi) * S + tb) = P.u;
        } else if (three == 0) {
          // Q: fold log2(e)/8 softmax scale here (free)
          bf16* dst = q + ((size_t)(bidx * NHEAD + head) * S + tb) * HDIM + hdi;
#pragma unroll
          for (int r = 0; r < 4; ++r)
            dst[(size_t)r * HDIM] = (bf16)((acc[im][in][r] + bv) * QSCALE);
        } else {
          bf16* dst = k + ((size_t)(bidx * NHEAD + head) * S + tb) * HDIM + hdi;
#pragma unroll
          for (int r = 0; r < 4; ++r) dst[(size_t)r * HDIM] = (bf16)(acc[im][in][r] + bv);
        }
      }
    }
  } else {
#pragma unroll
    for (int in = 0; in < 4; ++in) {
      int co = n0 + noff + in * 16 + ln;
      float bv = bias[co];
#pragma unroll
      for (int im = 0; im < 4; ++im) {
        int mbase = m0 + moff + im * 16 + quad * 4;
        int tb = mbase - bidx * S;
        float4 st;
        st.x = acc[im][in][0] + bv;
        st.y = acc[im][in][1] + bv;
        st.z = acc[im][in][2] + bv;
        st.w = acc[im][in][3] + bv;
        *(float4*)(outf + ((size_t)bidx * C + co) * S + tb) = st;
      }
    }
  }
}

// ---------------------------------------------------------------------------
// 3) causal attention, LDS-FREE: 256-q blocks x 8 independent waves
//   (32q/wave, 32x32x16 MFMA). K and V fragments are read DIRECTLY from
//   global (L2-resident, 16B-aligned) -- no staging, no barriers, no bank
//   conflicts. In-register P via cvt_pk_bf16 + permlane32_swap.
//   NO ATOMICS: chunks write partial (O,l) to their part slot (plain
//   stores); k_norm sums 2-3 parts. qt<=1 single-chunk -> direct z.
//   22 balanced chunks per bh (4-12 tiles), grid 704. Each wave iterates
//   only its own causal range [lo, min(hi, ktd+1)).
// ---------------------------------------------------------------------------
__global__ __launch_bounds__(512) void k_attn_part(const bf16* __restrict__ Qg,
                                                   const bf16* __restrict__ Kg,
                                                   const bf16* __restrict__ Vtg,
                                                   bf16* __restrict__ z,
                                                   float* __restrict__ Oacc,
                                                   float* __restrict__ Lacc) {
  // chunk table: r -> (qt, lo, hi, part), sizes 12..4 descending
  static const unsigned char QT[22] = {8,8,8,7,7,7,6,6,6,5,5,5,1,4,4,4,3,2,2,3,3,0};
  static const unsigned char LO[22] = {0,12,24,0,11,22,0,10,19,0,8,16,0,0,7,14,0,0,6,6,11,0};
  static const unsigned char HI[22] = {12,24,36,11,22,32,10,19,28,8,16,24,8,7,14,20,6,6,12,11,16,4};
  static const unsigned char PT[22] = {0,1,2,0,1,2,0,1,2,0,1,2,0,0,1,2,0,0,1,1,2,0};
  int i = blockIdx.x;
  int xcd = i & 7, j = i >> 3;      // j in [0,88)
  int grp = j / 22, r = j % 22;     // 4 bh per XCD (K+V 2.3 MB < 4 MB L2)
  int bh = xcd + 8 * grp;
  int qt = QT[r], lo = LO[r], hi = HI[r], part = PT[r];
  bool single = (qt <= 1);          // full-range chunk -> direct z
  int b = bh >> 4, h = bh & 15;
  int tid = threadIdx.x;
  int w = tid >> 6, lane = tid & 63;
  int ql = lane & 31, hw = lane >> 5;
  int qw = qt * 256 + w * 32;       // this wave's q base
  int qg = qw + ql;                 // this lane's q (col dim of 32x32)
  int ktd = qw >> 6;                // wave's diagonal k-tile = 4qt + (w>>1)
  int myhi = (hi < ktd + 1) ? hi : ktd + 1;   // per-wave causal end

  const bf16* kb = Kg + (size_t)bh * S * HDIM;
  const bf16* vb = Vtg + (size_t)bh * HDIM * S;

  // per-lane fragment base offsets (16B aligned)
  // K frag (block blk, chunk c): kb + (kt*64 + blk*32 + ql)*64 + c*16 + hw*8
  const bf16* kfb = kb + (size_t)ql * HDIM + hw * 8;
  // V frag (block blk, chunk ktc): vb + (blk*32+ql)*S + kt*64 + (2ktc+hw)*8
  const bf16* vfb = vb + (size_t)ql * S + hw * 8;

  // Q as B-operand (col=q=ql, k=hd): lane holds Q[qg][16c + hw*8 + j]
  const bf16* qb = Qg + ((size_t)bh * S + qg) * HDIM + hw * 8;
  bf16x8 qf[4];
#pragma unroll
  for (int c = 0; c < 4; ++c) qf[c] = *(const bf16x8*)(qb + c * 16);

  float lsA = 0.f, lsB = 0.f;
  floatx16 o0 = {}, o1 = {};        // O[hd = hdblk*32 + (r&3)+8*(r>>2)+4hw][q=ql]

#pragma unroll 1
  for (int kt = lo; kt < myhi; ++kt) {
    bool diag = (kt == ktd);
    const bf16* kt0 = kfb + (size_t)kt * 64 * HDIM;   // block 0 rows
    const bf16* vt0 = vfb + (size_t)kt * 64;          // block 0 hd rows

    // K fragments straight from global (L2-hit), then QK^T.
    bf16x8 kf0[4], kf1[4];
#pragma unroll
    for (int c = 0; c < 4; ++c) {
      kf0[c] = *(const bf16x8*)(kt0 + c * 16);
      kf1[c] = *(const bf16x8*)(kt0 + (size_t)32 * HDIM + c * 16);
    }
    floatx16 sa0 = {}, sa1 = {};
    __builtin_amdgcn_s_setprio(1);
#pragma unroll
    for (int c = 0; c < 4; ++c) {
      sa0 = __builtin_amdgcn_mfma_f32_32x32x16_bf16(kf0[c], qf[c], sa0, 0, 0, 0);
      sa1 = __builtin_amdgcn_mfma_f32_32x32x16_bf16(kf1[c], qf[c], sa1, 0, 0, 0);
    }
    __builtin_amdgcn_s_setprio(0);

    // V fragments: issue now; latency hides under the exp2/pack block.
    bf16x8 vf0[4], vf1[4];
#pragma unroll
    for (int ktc = 0; ktc < 4; ++ktc) {
      vf0[ktc] = *(const bf16x8*)(vt0 + ktc * 16);
      vf1[ktc] = *(const bf16x8*)(vt0 + (size_t)32 * S + ktc * 16);
    }

    // exp2 + pack to bf16 pairs. P[ktloc = (r&3)+8*(r>>2)+4hw][q=ql].
    unsigned pk0[8], pk1[8];
    if (!diag) {
#pragma unroll
      for (int t = 0; t < 8; ++t) {
        float a = exp2f(sa0[2 * t]), c2 = exp2f(sa0[2 * t + 1]);
        float d = exp2f(sa1[2 * t]), e = exp2f(sa1[2 * t + 1]);
        lsA += a + c2;
        lsB += d + e;
        pk0[t] = cvtpk(a, c2);
        pk1[t] = cvtpk(d, e);
      }
    } else {
      int qd = qg - kt * 64;        // local q within this diagonal 64-tile
#pragma unroll
      for (int t = 0; t < 8; ++t) {
        int r0 = 2 * t, r1 = 2 * t + 1;
        int k0l = (r0 & 3) + 8 * (r0 >> 2) + 4 * hw;
        int k1l = (r1 & 3) + 8 * (r1 >> 2) + 4 * hw;
        float a = (k0l > qd) ? 0.f : exp2f(sa0[r0]);
        float c2 = (k1l > qd) ? 0.f : exp2f(sa0[r1]);
        float d = (32 + k0l > qd) ? 0.f : exp2f(sa1[r0]);
        float e = (32 + k1l > qd) ? 0.f : exp2f(sa1[r1]);
        lsA += a + c2;
        lsB += d + e;
        pk0[t] = cvtpk(a, c2);
        pk1[t] = cvtpk(d, e);
      }
    }

    // Ot += V P : redistribute P across half-waves with permlane32_swap,
    // then A = Vt rows (hd), B = P (col=q, k=kt), 4 kt16-chunks.
    __builtin_amdgcn_s_setprio(1);
#pragma unroll
    for (int ktc = 0; ktc < 4; ++ktc) {
      unsigned d0, d1, d2, d3;
      if (ktc == 0)      { d0 = pk0[0]; d1 = pk0[1]; d2 = pk0[2]; d3 = pk0[3]; }
      else if (ktc == 1) { d0 = pk0[4]; d1 = pk0[5]; d2 = pk0[6]; d3 = pk0[7]; }
      else if (ktc == 2) { d0 = pk1[0]; d1 = pk1[1]; d2 = pk1[2]; d3 = pk1[3]; }
      else               { d0 = pk1[4]; d1 = pk1[5]; d2 = pk1[6]; d3 = pk1[7]; }
      pl32(d0, d2);   // d0 -> frag word0 (kt 8hw+0,1), d2 -> word2 (kt 8hw+4,5)
      pl32(d1, d3);   // d1 -> word1, d3 -> word3
      union { unsigned u[4]; bf16x8 v; } pf;
      pf.u[0] = d0; pf.u[1] = d1; pf.u[2] = d2; pf.u[3] = d3;
      o0 = __builtin_amdgcn_mfma_f32_32x32x16_bf16(vf0[ktc], pf.v, o0, 0, 0, 0);
      o1 = __builtin_amdgcn_mfma_f32_32x32x16_bf16(vf1[ktc], pf.v, o1, 0, 0, 0);
    }
    __builtin_amdgcn_s_setprio(0);
  }

  // l lives split across hw halves (same q in lanes ql and ql+32)
  float lsum = lsA + lsB;
  lsum += __shfl_xor(lsum, 32);

  if (single) {
    float inv = 1.f / lsum;
    bf16* dst = z + ((size_t)b * S + qg) * C + h * HDIM + 4 * hw;
#pragma unroll
    for (int hdblk = 0; hdblk < 2; ++hdblk) {
#pragma unroll
      for (int rg = 0; rg < 4; ++rg) {
        union { ushort4 u; bf16 hh[4]; } P;
#pragma unroll
        for (int jj = 0; jj < 4; ++jj) {
          float ov = hdblk ? o1[rg * 4 + jj] : o0[rg * 4 + jj];
          P.hh[jj] = (bf16)(ov * inv);
        }
        *(ushort4*)(dst + hdblk * 32 + rg * 8) = P.u;
      }
    }
  } else {
    // plain-store partial (O, l) into this chunk's part slot
    int qa = qg - QACC0;
    float* ob = Oacc + (((size_t)part * 32 + bh) * NACCQ + qa) * 64;
    if (hw == 0) Lacc[((size_t)part * 32 + bh) * NACCQ + qa] = lsum;
#pragma unroll
    for (int g = 0; g < 4; ++g) {
      *(float4*)(ob + 4 * hw + 8 * g) =
          float4{o0[4 * g], o0[4 * g + 1], o0[4 * g + 2], o0[4 * g + 3]};
      *(float4*)(ob + 32 + 4 * hw + 8 * g) =
          float4{o1[4 * g], o1[4 * g + 1], o1[4 * g + 2], o1[4 * g + 3]};
    }
  }
}

// ---------------------------------------------------------------------------
// merge/normalize: z[q][hd] = sum_p O_p / sum_p l_p   (2 parts for qt2,
//   3 parts for qt>=3). grid (28, 32). No LDS (layout matches output).
// ---------------------------------------------------------------------------
__global__ __launch_bounds__(256) void k_norm(const float* __restrict__ Oacc,
                                              const float* __restrict__ Lacc,
                                              bf16* __restrict__ z) {
  int qt = blockIdx.x, bh = blockIdx.y;
  int b = bh >> 4, h = bh & 15;
  int tid = threadIdx.x;
  int q = tid >> 2;                 // 0..63
  int seg = tid & 3;                // 16-hd segment
  int qa = qt * 64 + q;             // accum-space q
  bool np3 = (qa >= 256);           // global q >= 768 (qt>=3) has 3 parts
  float l = Lacc[(size_t)bh * NACCQ + qa] +
            Lacc[((size_t)32 + bh) * NACCQ + qa];
  if (np3) l += Lacc[((size_t)64 + bh) * NACCQ + qa];
  float inv = 1.f / l;
  const float* o0 = Oacc + ((size_t)bh * NACCQ + qa) * 64 + seg * 16;
  const float* o1 = Oacc + (((size_t)32 + bh) * NACCQ + qa) * 64 + seg * 16;
  const float* o2 = Oacc + (((size_t)64 + bh) * NACCQ + qa) * 64 + seg * 16;
  bf16* dst = z + ((size_t)b * S + QACC0 + qa) * C + h * HDIM + seg * 16;
#pragma unroll
  for (int half = 0; half < 2; ++half) {
    float4 a0 = *(const float4*)(o0 + half * 8);
    float4 a1 = *(const float4*)(o0 + half * 8 + 4);
    float4 b0 = *(const float4*)(o1 + half * 8);
    float4 b1 = *(const float4*)(o1 + half * 8 + 4);
    float s0 = a0.x + b0.x, s1 = a0.y + b0.y, s2 = a0.z + b0.z, s3 = a0.w + b0.w;
    float s4 = a1.x + b1.x, s5 = a1.y + b1.y, s6 = a1.z + b1.z, s7 = a1.w + b1.w;
    if (np3) {
      float4 c0 = *(const float4*)(o2 + half * 8);
      float4 c1 = *(const float4*)(o2 + half * 8 + 4);
      s0 += c0.x; s1 += c0.y; s2 += c0.z; s3 += c0.w;
      s4 += c1.x; s5 += c1.y; s6 += c1.z; s7 += c1.w;
    }
    bf16x8 o;
    o[0] = (bf16)(s0 * inv);
    o[1] = (bf16)(s1 * inv);
    o[2] = (bf16)(s2 * inv);
    o[3] = (bf16)(s3 * inv);
    o[4] = (bf16)(s4 * inv);
    o[5] = (bf16)(s5 * inv);
    o[6] = (bf16)(s6 * inv);
    o[7] = (bf16)(s7 * inv);
    *(bf16x8*)(dst + half * 8) = o;
  }
}

// ---------------------------------------------------------------------------
extern "C" void kernel_launch(void* const* d_in, const int* in_sizes, int n_in,
                              void* d_out, int out_size, void* d_ws, size_t ws_size,
                              hipStream_t stream) {
  const float* x    = (const float*)d_in[0];
  const float* Wqkv = (const float*)d_in[1];
  const float* bqkv = (const float*)d_in[2];
  const float* Wo   = (const float*)d_in[3];
  const float* bo   = (const float*)d_in[4];
  float* out = (float*)d_out;

  bf16* ws = (bf16*)d_ws;
  const size_t tok = (size_t)BATCH * S * C;          // 4,718,592 elems
  bf16* xs   = ws;                 // [b*S][C]  (reused as z after qkv gemm)
  bf16* Qg   = ws + tok;           // [bh][S][64]
  bf16* Kg   = ws + 2 * tok;       // [bh][S][64]
  bf16* Vtg  = ws + 3 * tok;       // [bh][64][S]
  bf16* Wqb  = ws + 4 * tok;       // [3072][1024] bf16
  bf16* Wob  = Wqb + (size_t)3 * C * C;  // [1024][1024] bf16
  float* Oacc = (float*)(Wob + (size_t)C * C);  // [3][32][NACCQ][64] fp32
  float* Lacc = Oacc + (size_t)NPART * 32 * NACCQ * 64;  // [3][32][NACCQ]
  bf16* z    = xs;

  k_convert<<<(3 * C * C / 8 + 255) / 256, 256, 0, stream>>>(Wqkv, Wqb, 3 * C * C / 8);
  k_convert<<<(C * C / 8 + 255) / 256, 256, 0, stream>>>(Wo, Wob, C * C / 8);
  k_transpose<<<dim3(C / 64, S / 64, BATCH), 256, 0, stream>>>(x, xs);
  k_gemm_bt<0><<<dim3(3 * C / 128, BATCH * S / 128), 256, 0, stream>>>(
      xs, Wqb, bqkv, Qg, Kg, Vtg, nullptr);
  k_attn_part<<<dim3(704), 512, 0, stream>>>(Qg, Kg, Vtg, z, Oacc, Lacc);
  k_norm<<<dim3(28, 32), 256, 0, stream>>>(Oacc, Lacc, z);
  k_gemm_bt<1><<<dim3(C / 128, BATCH * S / 128), 256, 0, stream>>>(
      z, Wob, bo, nullptr, nullptr, nullptr, out);
}

// Round 8
// 217.749 us; speedup vs baseline: 1.2356x; 1.2356x over previous
//
#include <hip/hip_runtime.h>

typedef __bf16 bf16;
typedef __bf16 bf16x8 __attribute__((ext_vector_type(8)));
typedef float floatx4 __attribute__((ext_vector_type(4)));
typedef float floatx16 __attribute__((ext_vector_type(16)));

static constexpr int S = 2304;     // 48*48 tokens
static constexpr int C = 1024;
static constexpr int NHEAD = 16;
static constexpr int HDIM = 64;
static constexpr int BATCH = 2;
static constexpr float QSCALE = 0.18033688011112042f;  // log2(e)/8
static constexpr int QACC0 = 768;  // accum space starts at q=768 (qt>=3)
static constexpr int NACCQ = S - QACC0;  // 1536 accum q slots
static constexpr int NPART = 3;    // up to 3 k-chunks per accum q-row

// ---------------------------------------------------------------------------
// 0) fp32 -> bf16 convert (weights)
// ---------------------------------------------------------------------------
__global__ __launch_bounds__(256) void k_convert(const float* __restrict__ src,
                                                 bf16* __restrict__ dst, int n8) {
  int i = blockIdx.x * 256 + threadIdx.x;
  if (i >= n8) return;
  float4 a = *(const float4*)(src + (size_t)i * 8);
  float4 b = *(const float4*)(src + (size_t)i * 8 + 4);
  bf16x8 o;
  o[0] = (bf16)a.x; o[1] = (bf16)a.y; o[2] = (bf16)a.z; o[3] = (bf16)a.w;
  o[4] = (bf16)b.x; o[5] = (bf16)b.y; o[6] = (bf16)b.z; o[7] = (bf16)b.w;
  *(bf16x8*)(dst + (size_t)i * 8) = o;
}

// ---------------------------------------------------------------------------
// 1) transpose + cast: x[b][c][t] (fp32) -> xs[(b*S+t)][c] (bf16)
// ---------------------------------------------------------------------------
__global__ __launch_bounds__(256) void k_transpose(const float* __restrict__ x,
                                                   bf16* __restrict__ xs) {
  __shared__ bf16 T[64 * 72];   // [t][c] tile, stride 72
  int c0 = blockIdx.x * 64, t0 = blockIdx.y * 64, b = blockIdx.z;
  int tid = threadIdx.x;
  const float* xb = x + (size_t)b * C * S;
#pragma unroll
  for (int it = 0; it < 4; ++it) {
    int idx = it * 256 + tid;            // 1024 float4 chunks
    int rc = idx >> 4, t4 = idx & 15;    // c-row, t-group-of-4
    float4 v = *(const float4*)(xb + (size_t)(c0 + rc) * S + t0 + t4 * 4);
    T[(t4 * 4 + 0) * 72 + rc] = (bf16)v.x;
    T[(t4 * 4 + 1) * 72 + rc] = (bf16)v.y;
    T[(t4 * 4 + 2) * 72 + rc] = (bf16)v.z;
    T[(t4 * 4 + 3) * 72 + rc] = (bf16)v.w;
  }
  __syncthreads();
  bf16* xsb = xs + (size_t)b * S * C;
#pragma unroll
  for (int it = 0; it < 2; ++it) {
    int idx = it * 256 + tid;            // 512 chunks of 8 c
    int rt = idx >> 3, c8 = idx & 7;
    bf16x8 v;
#pragma unroll
    for (int i = 0; i < 8; ++i) v[i] = T[rt * 72 + c8 * 8 + i];
    *(bf16x8*)(xsb + (size_t)(t0 + rt) * C + c0 + c8 * 8) = v;
  }
}

// ---------------------------------------------------------------------------
// async global->LDS 16B helper
// ---------------------------------------------------------------------------
__device__ __forceinline__ void g2l16(const bf16* g, bf16* l) {
  __builtin_amdgcn_global_load_lds(
      (const __attribute__((address_space(1))) void*)g,
      (__attribute__((address_space(3))) void*)l, 16, 0, 0);
}

// pack 2 f32 -> 1 dword of 2 bf16 (RNE)
__device__ __forceinline__ unsigned cvtpk(float a, float b) {
  unsigned r;
  asm("v_cvt_pk_bf16_f32 %0, %1, %2" : "=v"(r) : "v"(a), "v"(b));
  return r;
}

// swap a.hi32lanes <-> b.lo32lanes
__device__ __forceinline__ void pl32(unsigned& a, unsigned& b) {
  asm("v_permlane32_swap_b32 %0, %1" : "+v"(a), "+v"(b));
}

// ---------------------------------------------------------------------------
// 2/4) GEMM  C[m][n] = A[m][:] . Bt[n][:]  (+fp32 bias, fused epilogue)
//   128x128 tile, BK=64, XOR-swizzled 16B chunks, 32 MFMA per barrier pair,
//   16 K-iterations.   [R5 proven version]
//   EPI 0: qkv -> Q (pre-scaled by log2e/8), K, Vt
//   EPI 1: out-proj -> out[b][co][t] fp32
// ---------------------------------------------------------------------------
template <int EPI>
__global__ __launch_bounds__(256) void k_gemm_bt(const bf16* __restrict__ A,
                                                 const bf16* __restrict__ Bt,
                                                 const float* __restrict__ bias,
                                                 bf16* __restrict__ q,
                                                 bf16* __restrict__ k,
                                                 bf16* __restrict__ v,
                                                 float* __restrict__ outf) {
  constexpr int K = C;
  __shared__ bf16 As[128 * 64];     // [row][64], chunks XOR-swizzled
  __shared__ bf16 Bs[128 * 64];
  int tid = threadIdx.x;
  int w = tid >> 6, lane = tid & 63, ln = lane & 15, quad = lane >> 4;
  int m0 = blockIdx.y * 128, n0 = blockIdx.x * 128;
  int moff = (w >> 1) * 64, noff = (w & 1) * 64;
  floatx4 acc[4][4] = {};

  // staging map: 1024 chunks of 16B per matrix; thread covers 4 each.
  int sr[4], sc[4];
#pragma unroll
  for (int it = 0; it < 4; ++it) {
    int L = (it * 4 + w) * 64 + lane;
    sr[it] = L >> 3;
    sc[it] = (L & 7) ^ (sr[it] & 7);
  }

  for (int k0 = 0; k0 < K; k0 += 64) {
    __syncthreads();
#pragma unroll
    for (int it = 0; it < 4; ++it) {
      int cb = (it * 4 + w) * 64;       // wave-uniform chunk base
      g2l16(A + (size_t)(m0 + sr[it]) * K + k0 + sc[it] * 8, As + cb * 8);
      g2l16(Bt + (size_t)(n0 + sr[it]) * K + k0 + sc[it] * 8, Bs + cb * 8);
    }
    __syncthreads();
#pragma unroll
    for (int t = 0; t < 2; ++t) {       // two k-halves of 32
      bf16x8 af[4], bfr[4];
#pragma unroll
      for (int i = 0; i < 4; ++i) {
        int ra = moff + i * 16 + ln;
        af[i]  = *(const bf16x8*)(As + ra * 64 + (((t * 4 + quad) ^ (ra & 7))) * 8);
        int rb = noff + i * 16 + ln;
        bfr[i] = *(const bf16x8*)(Bs + rb * 64 + (((t * 4 + quad) ^ (rb & 7))) * 8);
      }
#pragma unroll
      for (int im = 0; im < 4; ++im)
#pragma unroll
        for (int in = 0; in < 4; ++in)
          acc[im][in] = __builtin_amdgcn_mfma_f32_16x16x32_bf16(
              af[im], bfr[in], acc[im][in], 0, 0, 0);
    }
  }

  int bidx = (m0 >= S) ? 1 : 0;   // S=2304 = 18*128: tiles never straddle
  if (EPI == 0) {
#pragma unroll
    for (int in = 0; in < 4; ++in) {
      int j = n0 + noff + in * 16 + ln;    // column in [0,3072)
      float bv = bias[j];
      int three = j >> 10;
      int head = (j >> 6) & 15;
      int hdi = j & 63;
#pragma unroll
      for (int im = 0; im < 4; ++im) {
        int mbase = m0 + moff + im * 16 + quad * 4;
        int tb = mbase - bidx * S;
        if (three == 2) {
          union { ushort4 u; bf16 h[4]; } P;
#pragma unroll
          for (int r = 0; r < 4; ++r) P.h[r] = (bf16)(acc[im][in][r] + bv);
          *(ushort4*)(v + ((size_t)(bidx * NHEAD + head) * HDIM + hdi) * S + tb) = P.u;
        } else if (three == 0) {
          // Q: fold log2(e)/8 softmax scale here (free)
          bf16* dst = q + ((size_t)(bidx * NHEAD + head) * S + tb) * HDIM + hdi;
#pragma unroll
          for (int r = 0; r < 4; ++r)
            dst[(size_t)r * HDIM] = (bf16)((acc[im][in][r] + bv) * QSCALE);
        } else {
          bf16* dst = k + ((size_t)(bidx * NHEAD + head) * S + tb) * HDIM + hdi;
#pragma unroll
          for (int r = 0; r < 4; ++r) dst[(size_t)r * HDIM] = (bf16)(acc[im][in][r] + bv);
        }
      }
    }
  } else {
#pragma unroll
    for (int in = 0; in < 4; ++in) {
      int co = n0 + noff + in * 16 + ln;
      float bv = bias[co];
#pragma unroll
      for (int im = 0; im < 4; ++im) {
        int mbase = m0 + moff + im * 16 + quad * 4;
        int tb = mbase - bidx * S;
        float4 st;
        st.x = acc[im][in][0] + bv;
        st.y = acc[im][in][1] + bv;
        st.z = acc[im][in][2] + bv;
        st.w = acc[im][in][3] + bv;
        *(float4*)(outf + ((size_t)bidx * C + co) * S + tb) = st;
      }
    }
  }
}

// ---------------------------------------------------------------------------
// 3) causal attention, 256-q blocks x 8 waves (32q/wave, 32x32x16 MFMA),
//   in-register P via cvt_pk_bf16 + permlane32_swap.
//   128-kt SUPER-TILES, double-buffered (64KB LDS): per super-tile
//   {issue stage(next) -> compute 2 sub-tiles -> vmcnt(0) (hidden under
//   compute) -> s_barrier}. Half the barriers of the 64-kt version.
//   NO ATOMICS: parts written with plain stores; k_norm sums 2-3 parts.
//   18 chunks/bh (sizes 4-12, even), grid 576; smallest chunk types last
//   in dispatch order (they are the 64 over-capacity blocks at 2 blk/CU).
// ---------------------------------------------------------------------------
__global__ __launch_bounds__(512) void k_attn_part(const bf16* __restrict__ Qg,
                                                   const bf16* __restrict__ Kg,
                                                   const bf16* __restrict__ Vtg,
                                                   bf16* __restrict__ z,
                                                   float* __restrict__ Oacc,
                                                   float* __restrict__ Lacc) {
  __shared__ bf16 Ks[2][128 * 64];  // [kt 0..127][hd], 16B chunks XOR-swz/row
  __shared__ bf16 Vs[2][64 * 128];  // [hd][kt 0..127], c16 XOR-swz/row
  // chunk table: r -> (qt, lo, hi, part); all lo/hi even; qt<=2 single.
  static const unsigned char QT[18] = {8,8,8,7,7,7,6,6,6,5,5,4,4,3,3,2,1,0};
  static const unsigned char LO[18] = {0,12,24,0,12,22,0,10,20,0,12,0,10,0,8,0,0,0};
  static const unsigned char HI[18] = {12,24,36,12,22,32,10,20,28,12,24,10,20,8,16,12,8,4};
  static const unsigned char PT[18] = {0,1,2,0,1,2,0,1,2,0,1,0,1,0,1,0,0,0};
  int i = blockIdx.x;
  int xcd = i & 7, j = i >> 3;      // j in [0,72)
  int r = j >> 2, grp = j & 3;      // r = chunk type, 4 bh per XCD
  int bh = xcd + 8 * grp;
  int qt = QT[r], lo = LO[r], hi = HI[r], part = PT[r];
  bool single = (qt <= 2);          // full-range chunk -> direct z
  int b = bh >> 4, h = bh & 15;
  int tid = threadIdx.x;
  int w = tid >> 6, lane = tid & 63;
  int ql = lane & 31, hw = lane >> 5;
  int qw = qt * 256 + w * 32;       // this wave's q base
  int qg = qw + ql;                 // this lane's q (col dim of 32x32)
  int ktd = qw >> 6;                // wave's diagonal k-tile = 4qt + (w>>1)

  const bf16* kb = Kg + (size_t)bh * S * HDIM;
  const bf16* vb = Vtg + (size_t)bh * HDIM * S;

  // staging: 1024 chunks of 16B per K/V super-tile; 2 K + 2 V per thread.
  // K LDS[row 0..127][c8^(row&7)]: chunk tid -> row tid>>3; +512 -> row+64.
  int kr = tid >> 3;
  int kc = (tid & 7) ^ (kr & 7);
  size_t kOff1 = (size_t)kr * HDIM + kc * 8;
  size_t kOff2 = kOff1 + (size_t)64 * HDIM;   // (row+64)&7 == row&7
  // V LDS[row 0..63][c16^(row&7)]: chunk tid -> row tid>>4; +512 -> row+32.
  int vr = tid >> 4;
  int vc = (tid & 15) ^ (vr & 7);
  size_t vOff1 = (size_t)vr * S + vc * 8;
  size_t vOff2 = vOff1 + (size_t)32 * S;      // (row+32)&7 == row&7

  // Q as B-operand (col=q=ql, k=hd): lane holds Q[qg][16c + hw*8 + j]
  const bf16* qb = Qg + ((size_t)bh * S + qg) * HDIM + hw * 8;
  bf16x8 qf[4];
#pragma unroll
  for (int c = 0; c < 4; ++c) qf[c] = *(const bf16x8*)(qb + c * 16);

  float lsA = 0.f, lsB = 0.f;
  floatx16 o0 = {}, o1 = {};        // O[hd = hdblk*32 + (r&3)+8*(r>>2)+4hw][q=ql]

  int nst = (hi - lo) >> 1;         // super-tiles (sizes are even)
  const bf16* kb0 = kb + (size_t)lo * 64 * HDIM;
  const bf16* vb0 = vb + (size_t)lo * 64;
  // prologue: stage super-tile 0 into buffer 0
  g2l16(kb0 + kOff1, Ks[0] + tid * 8);
  g2l16(kb0 + kOff2, Ks[0] + (512 + tid) * 8);
  g2l16(vb0 + vOff1, Vs[0] + tid * 8);
  g2l16(vb0 + vOff2, Vs[0] + (512 + tid) * 8);
  asm volatile("s_waitcnt vmcnt(0)" ::: "memory");
  __builtin_amdgcn_s_barrier();

  const bf16* kbn = kb0 + (size_t)128 * HDIM;
  const bf16* vbn = vb0 + 128;
  int qsw = ql & 7;                 // read-side XOR swizzle key
  int cur = 0;

#pragma unroll 1
  for (int st = 0; st < nst; ++st) {
    if (st + 1 < nst) {             // issue next super-tile's staging now;
      bf16* kd = Ks[cur ^ 1];       // buf cur^1 was released by last barrier
      bf16* vd = Vs[cur ^ 1];
      g2l16(kbn + kOff1, kd + tid * 8);
      g2l16(kbn + kOff2, kd + (512 + tid) * 8);
      g2l16(vbn + vOff1, vd + tid * 8);
      g2l16(vbn + vOff2, vd + (512 + tid) * 8);
      kbn += (size_t)128 * HDIM;
      vbn += 128;
    }
    const bf16* ksb = Ks[cur];
    const bf16* vsb = Vs[cur];
    int ktbase = lo + 2 * st;

#pragma unroll
    for (int hh = 0; hh < 2; ++hh) {   // two 64-kt sub-tiles
      int kt = ktbase + hh;
      if (kt > ktd) continue;          // above this wave's diagonal
      bool diag = (kt == ktd);

      // St = K Qt : A = K rows (kt), B = Q cols (q); two 32-kt blocks.
      floatx16 sa0 = {}, sa1 = {};
      __builtin_amdgcn_s_setprio(1);
#pragma unroll
      for (int c = 0; c < 4; ++c) {
        int c8 = ((2 * c + hw) ^ qsw) * 8;
        bf16x8 k0 = *(const bf16x8*)(ksb + (hh * 64 + ql) * 64 + c8);
        bf16x8 k1 = *(const bf16x8*)(ksb + (hh * 64 + 32 + ql) * 64 + c8);
        sa0 = __builtin_amdgcn_mfma_f32_32x32x16_bf16(k0, qf[c], sa0, 0, 0, 0);
        sa1 = __builtin_amdgcn_mfma_f32_32x32x16_bf16(k1, qf[c], sa1, 0, 0, 0);
      }
      __builtin_amdgcn_s_setprio(0);

      // exp2 + pack to bf16 pairs. P[ktloc = (r&3)+8*(r>>2)+4hw][q=ql].
      unsigned pk0[8], pk1[8];
      if (!diag) {
#pragma unroll
        for (int t = 0; t < 8; ++t) {
          float a = exp2f(sa0[2 * t]), c2 = exp2f(sa0[2 * t + 1]);
          float d = exp2f(sa1[2 * t]), e = exp2f(sa1[2 * t + 1]);
          lsA += a + c2;
          lsB += d + e;
          pk0[t] = cvtpk(a, c2);
          pk1[t] = cvtpk(d, e);
        }
      } else {
        int qd = qg - kt * 64;      // local q within this diagonal 64-tile
#pragma unroll
        for (int t = 0; t < 8; ++t) {
          int r0 = 2 * t, r1 = 2 * t + 1;
          int k0l = (r0 & 3) + 8 * (r0 >> 2) + 4 * hw;
          int k1l = (r1 & 3) + 8 * (r1 >> 2) + 4 * hw;
          float a = (k0l > qd) ? 0.f : exp2f(sa0[r0]);
          float c2 = (k1l > qd) ? 0.f : exp2f(sa0[r1]);
          float d = (32 + k0l > qd) ? 0.f : exp2f(sa1[r0]);
          float e = (32 + k1l > qd) ? 0.f : exp2f(sa1[r1]);
          lsA += a + c2;
          lsB += d + e;
          pk0[t] = cvtpk(a, c2);
          pk1[t] = cvtpk(d, e);
        }
      }

      // Ot += V P : permlane32_swap redistribution, then 4 kt16-chunks.
      __builtin_amdgcn_s_setprio(1);
#pragma unroll
      for (int ktc = 0; ktc < 4; ++ktc) {
        unsigned d0, d1, d2, d3;
        if (ktc == 0)      { d0 = pk0[0]; d1 = pk0[1]; d2 = pk0[2]; d3 = pk0[3]; }
        else if (ktc == 1) { d0 = pk0[4]; d1 = pk0[5]; d2 = pk0[6]; d3 = pk0[7]; }
        else if (ktc == 2) { d0 = pk1[0]; d1 = pk1[1]; d2 = pk1[2]; d3 = pk1[3]; }
        else               { d0 = pk1[4]; d1 = pk1[5]; d2 = pk1[6]; d3 = pk1[7]; }
        pl32(d0, d2);
        pl32(d1, d3);
        union { unsigned u[4]; bf16x8 v; } pf;
        pf.u[0] = d0; pf.u[1] = d1; pf.u[2] = d2; pf.u[3] = d3;
        int c16 = hh * 8 + ((2 * ktc + hw) ^ qsw);
        bf16x8 v0 = *(const bf16x8*)(vsb + ql * 128 + c16 * 8);
        bf16x8 v1 = *(const bf16x8*)(vsb + (32 + ql) * 128 + c16 * 8);
        o0 = __builtin_amdgcn_mfma_f32_32x32x16_bf16(v0, pf.v, o0, 0, 0, 0);
        o1 = __builtin_amdgcn_mfma_f32_32x32x16_bf16(v1, pf.v, o1, 0, 0, 0);
      }
      __builtin_amdgcn_s_setprio(0);
    }

    if (st + 1 < nst) {             // drain this iter's staging (landed under
      asm volatile("s_waitcnt vmcnt(0)" ::: "memory");   // the compute above)
      __builtin_amdgcn_s_barrier();
      cur ^= 1;
    }
  }

  // l lives split across hw halves (same q in lanes ql and ql+32)
  float lsum = lsA + lsB;
  lsum += __shfl_xor(lsum, 32);

  if (single) {
    float inv = 1.f / lsum;
    bf16* dst = z + ((size_t)b * S + qg) * C + h * HDIM + 4 * hw;
#pragma unroll
    for (int hdblk = 0; hdblk < 2; ++hdblk) {
#pragma unroll
      for (int rg = 0; rg < 4; ++rg) {
        union { ushort4 u; bf16 hh[4]; } P;
#pragma unroll
        for (int jj = 0; jj < 4; ++jj) {
          float ov = hdblk ? o1[rg * 4 + jj] : o0[rg * 4 + jj];
          P.hh[jj] = (bf16)(ov * inv);
        }
        *(ushort4*)(dst + hdblk * 32 + rg * 8) = P.u;
      }
    }
  } else {
    // plain-store partial (O, l) into this chunk's part slot
    int qa = qg - QACC0;
    float* ob = Oacc + (((size_t)part * 32 + bh) * NACCQ + qa) * 64;
    if (hw == 0) Lacc[((size_t)part * 32 + bh) * NACCQ + qa] = lsum;
#pragma unroll
    for (int g = 0; g < 4; ++g) {
      *(float4*)(ob + 4 * hw + 8 * g) =
          float4{o0[4 * g], o0[4 * g + 1], o0[4 * g + 2], o0[4 * g + 3]};
      *(float4*)(ob + 32 + 4 * hw + 8 * g) =
          float4{o1[4 * g], o1[4 * g + 1], o1[4 * g + 2], o1[4 * g + 3]};
    }
  }
}

// ---------------------------------------------------------------------------
// merge/normalize: z[q][hd] = sum_p O_p / sum_p l_p   (2 parts for qt3-5,
//   3 parts for qt>=6). grid (24, 32). No LDS (layout matches output).
// ---------------------------------------------------------------------------
__global__ __launch_bounds__(256) void k_norm(const float* __restrict__ Oacc,
                                              const float* __restrict__ Lacc,
                                              bf16* __restrict__ z) {
  int qt = blockIdx.x, bh = blockIdx.y;
  int b = bh >> 4, h = bh & 15;
  int tid = threadIdx.x;
  int q = tid >> 2;                 // 0..63
  int seg = tid & 3;                // 16-hd segment
  int qa = qt * 64 + q;             // accum-space q
  bool np3 = (qa >= 768);           // global q >= 1536 (qt>=6) has 3 parts
  float l = Lacc[(size_t)bh * NACCQ + qa] +
            Lacc[((size_t)32 + bh) * NACCQ + qa];
  if (np3) l += Lacc[((size_t)64 + bh) * NACCQ + qa];
  float inv = 1.f / l;
  const float* o0 = Oacc + ((size_t)bh * NACCQ + qa) * 64 + seg * 16;
  const float* o1 = Oacc + (((size_t)32 + bh) * NACCQ + qa) * 64 + seg * 16;
  const float* o2 = Oacc + (((size_t)64 + bh) * NACCQ + qa) * 64 + seg * 16;
  bf16* dst = z + ((size_t)b * S + QACC0 + qa) * C + h * HDIM + seg * 16;
#pragma unroll
  for (int half = 0; half < 2; ++half) {
    float4 a0 = *(const float4*)(o0 + half * 8);
    float4 a1 = *(const float4*)(o0 + half * 8 + 4);
    float4 b0 = *(const float4*)(o1 + half * 8);
    float4 b1 = *(const float4*)(o1 + half * 8 + 4);
    float s0 = a0.x + b0.x, s1 = a0.y + b0.y, s2 = a0.z + b0.z, s3 = a0.w + b0.w;
    float s4 = a1.x + b1.x, s5 = a1.y + b1.y, s6 = a1.z + b1.z, s7 = a1.w + b1.w;
    if (np3) {
      float4 c0 = *(const float4*)(o2 + half * 8);
      float4 c1 = *(const float4*)(o2 + half * 8 + 4);
      s0 += c0.x; s1 += c0.y; s2 += c0.z; s3 += c0.w;
      s4 += c1.x; s5 += c1.y; s6 += c1.z; s7 += c1.w;
    }
    bf16x8 o;
    o[0] = (bf16)(s0 * inv);
    o[1] = (bf16)(s1 * inv);
    o[2] = (bf16)(s2 * inv);
    o[3] = (bf16)(s3 * inv);
    o[4] = (bf16)(s4 * inv);
    o[5] = (bf16)(s5 * inv);
    o[6] = (bf16)(s6 * inv);
    o[7] = (bf16)(s7 * inv);
    *(bf16x8*)(dst + half * 8) = o;
  }
}

// ---------------------------------------------------------------------------
extern "C" void kernel_launch(void* const* d_in, const int* in_sizes, int n_in,
                              void* d_out, int out_size, void* d_ws, size_t ws_size,
                              hipStream_t stream) {
  const float* x    = (const float*)d_in[0];
  const float* Wqkv = (const float*)d_in[1];
  const float* bqkv = (const float*)d_in[2];
  const float* Wo   = (const float*)d_in[3];
  const float* bo   = (const float*)d_in[4];
  float* out = (float*)d_out;

  bf16* ws = (bf16*)d_ws;
  const size_t tok = (size_t)BATCH * S * C;          // 4,718,592 elems
  bf16* xs   = ws;                 // [b*S][C]  (reused as z after qkv gemm)
  bf16* Qg   = ws + tok;           // [bh][S][64]
  bf16* Kg   = ws + 2 * tok;       // [bh][S][64]
  bf16* Vtg  = ws + 3 * tok;       // [bh][64][S]
  bf16* Wqb  = ws + 4 * tok;       // [3072][1024] bf16
  bf16* Wob  = Wqb + (size_t)3 * C * C;  // [1024][1024] bf16
  float* Oacc = (float*)(Wob + (size_t)C * C);  // [3][32][NACCQ][64] fp32
  float* Lacc = Oacc + (size_t)NPART * 32 * NACCQ * 64;  // [3][32][NACCQ]
  bf16* z    = xs;

  k_convert<<<(3 * C * C / 8 + 255) / 256, 256, 0, stream>>>(Wqkv, Wqb, 3 * C * C / 8);
  k_convert<<<(C * C / 8 + 255) / 256, 256, 0, stream>>>(Wo, Wob, C * C / 8);
  k_transpose<<<dim3(C / 64, S / 64, BATCH), 256, 0, stream>>>(x, xs);
  k_gemm_bt<0><<<dim3(3 * C / 128, BATCH * S / 128), 256, 0, stream>>>(
      xs, Wqb, bqkv, Qg, Kg, Vtg, nullptr);
  k_attn_part<<<dim3(576), 512, 0, stream>>>(Qg, Kg, Vtg, z, Oacc, Lacc);
  k_norm<<<dim3(24, 32), 256, 0, stream>>>(Oacc, Lacc, z);
  k_gemm_bt<1><<<dim3(C / 128, BATCH * S / 128), 256, 0, stream>>>(
      z, Wob, bo, nullptr, nullptr, nullptr, out);
}